// Round 17
// baseline (94.436 us; speedup 1.0000x reference)
//
#include <hip/hip_runtime.h>
#include <math.h>

#define SRATE 32000.f
#define NB 128            // batch rows
#define NT 160000         // samples per row
#define CL 25             // samples per chunk (one per thread)
#define TPB 256           // threads per block (4 waves)
#define TILEF (TPB*CL)    // 6400 floats per tile (25.6 KB)
#define NCROW 6400        // chunks per row
#define BPR 25            // blocks per row (NCROW/TPB)
#define NBLK (NB*BPR)     // 3200 blocks for eq_a/eq_c
#define SEG 25            // chunks per thread in eq_b scan (NCROW/TPB)
#define RECROW (NCROW*8)  // floats per row in eoT/sgD (51200)

#ifndef M_PI
#define M_PI 3.14159265358979323846
#endif

// f32 coefficients, reference formula (hardware transcendentals).
__device__ __forceinline__ void coeffs_f32(
    const float* fr, const float* gn, const float* qs, float* c)
{
  #pragma unroll
  for (int f = 0; f < 3; ++f) {
    float w0 = 2.f * (float)M_PI * fr[f] / SRATE;
    float A  = expf(gn[f] * (2.302585093f / 40.f));   // 10^(g/40)
    float al = sinf(w0) / (2.f * qs[f]);
    float cw = cosf(w0);
    float a0 = 1.f + al / A;
    c[f*5+0] = (1.f + al*A) / a0;
    c[f*5+1] = -2.f * cw / a0;
    c[f*5+2] = (1.f - al*A) / a0;
    c[f*5+3] = -2.f * cw / a0;
    c[f*5+4] = (1.f - al/A) / a0;
  }
}

// one cascade step; res <- y3 (pre-shift)
#define STEPR(xn, res) do { \
    float y1 = c[0]*(xn) + c[1]*x1  + c[2]*x2   - c[3]*y1p  - c[4]*y1pp;  \
    float y2 = c[5]*y1  + c[6]*y1p + c[7]*y1pp - c[8]*y2p  - c[9]*y2pp;   \
    float y3 = c[10]*y2 + c[11]*y2p + c[12]*y2pp - c[13]*y3p - c[14]*y3pp;\
    (res) = y3;                                                            \
    x2 = x1; x1 = (xn);                                                    \
    y1pp=y1p; y1p=y1; y2pp=y2p; y2p=y2; y3pp=y3p; y3p=y3;                  \
  } while (0)

// ---------------------------------------------------------------------------
// A: 4-wave LDS-tile zero-entry-state IIR. coop-load x -> per-thread 25-sample
// IIR on own stride-25 row (scalar b32, 2-way bank alias = free) -> exit
// record to TRANSPOSED eoT[row][(ci%25)*256 + ci/25] (eq_b reads coalesced).
// ---------------------------------------------------------------------------
__global__ __launch_bounds__(TPB) void eq_a(
    const float* __restrict__ x, const float* __restrict__ fr,
    const float* __restrict__ gn, const float* __restrict__ qs,
    float* __restrict__ eoT)
{
  __shared__ float lds[TILEF];          // 25.6 KB
  const int tid = threadIdx.x;
  const int b = blockIdx.x;
  const int row = b / BPR;
  const int ci = (b % BPR) * TPB + tid;
  float c[15];
  coeffs_f32(fr, gn, qs, c);
  const float4* xg4 = (const float4*)(x + (size_t)b * TILEF);
  float4* l4 = (float4*)lds;
  #pragma unroll
  for (int it = 0; it < 6; ++it) l4[it*TPB + tid] = xg4[it*TPB + tid];
  if (tid < 64) l4[1536 + tid] = xg4[1536 + tid];
  __syncthreads();
  float x1, x2;
  if (tid == 0) {
    if (ci == 0) { x1 = 0.f; x2 = 0.f; }
    else {
      float2 h = *(const float2*)(x + (size_t)b * TILEF - 2);
      x1 = h.y; x2 = h.x;
    }
  } else {
    x1 = lds[tid*CL - 1]; x2 = lds[tid*CL - 2];
  }
  float y1p=0,y1pp=0,y2p=0,y2pp=0,y3p=0,y3pp=0;
  #pragma unroll
  for (int k = 0; k < CL; ++k) {
    float d_; STEPR(lds[tid*CL + k], d_); (void)d_;
  }
  const int plane = ci % 25, slot = ci / 25;
  float* ep = eoT + (size_t)row * RECROW + ((size_t)(plane*TPB + slot))*8;
  float4 r0; r0.x=y1p; r0.y=y1pp; r0.z=y2p; r0.w=y2pp;
  float4 r1; r1.x=y3p; r1.y=y3pp; r1.z=0.f; r1.w=0.f;
  *(float4*)ep = r0; *(float4*)(ep+4) = r1;
}

// ---------------------------------------------------------------------------
// B: one 256-thread block per row (r13-verified in-block machinery).
// Prologue (f64): Hc = M^25, A = Hc^25, Gs[k] = A^(2^k) k=0..5, W64 = A^64.
// Thread t owns chunks t*25+jj: local scan (coalesced transposed reads) ->
// wave KS (A-powers) -> cross-wave wtot combine -> lane-0 injection + KS#2 ->
// replay writes true entries to sgD[row][chunk] (direct; eq_c reads coalesced).
// ---------------------------------------------------------------------------
__global__ __launch_bounds__(TPB) void eq_b(
    const float* __restrict__ fr, const float* __restrict__ gn,
    const float* __restrict__ qs, const float* __restrict__ eoT,
    float* __restrict__ sgD)
{
  __shared__ double Mb[36], Rb[36], Tb[36];
  __shared__ float Hs[36], Gs[6*36], W64[36];
  __shared__ float wtot[4][8];
  const int tid = threadIdx.x, lane = tid & 63, w = tid >> 6;
  const int row = blockIdx.x;
  float c[15];
  coeffs_f32(fr, gn, qs, c);
  if (tid < 6) {   // one-step homogeneous matrix M, column tid
    double s0=0,s1=0,s2=0,s3=0,s4=0,s5=0;
    if (tid==0) s0=1; else if (tid==1) s1=1; else if (tid==2) s2=1;
    else if (tid==3) s3=1; else if (tid==4) s4=1; else s5=1;
    double y1 = -(double)c[3]*s0 - (double)c[4]*s1;
    double y2 = (double)c[5]*y1 + (double)c[6]*s0 + (double)c[7]*s1
              - (double)c[8]*s2 - (double)c[9]*s3;
    double y3 = (double)c[10]*y2 + (double)c[11]*s2 + (double)c[12]*s3
              - (double)c[13]*s4 - (double)c[14]*s5;
    Mb[0*6+tid]=y1; Mb[1*6+tid]=s0; Mb[2*6+tid]=y2;
    Mb[3*6+tid]=s2; Mb[4*6+tid]=y3; Mb[5*6+tid]=s4;
  }
  if (tid < 36) Rb[tid] = ((tid % 7) == 0) ? 1.0 : 0.0;
  __syncthreads();
  const int i = tid / 6, j = tid % 6;
  int e = CL;                                 // Rb = M^25 = Hc
  while (e) {
    if (e & 1) {
      double acc = 0.0;
      if (tid < 36) { for (int k = 0; k < 6; ++k) acc += Rb[i*6+k]*Mb[k*6+j]; Tb[tid]=acc; }
      __syncthreads();
      if (tid < 36) Rb[tid] = Tb[tid];
      __syncthreads();
    }
    e >>= 1;
    if (e) {
      double acc = 0.0;
      if (tid < 36) { for (int k = 0; k < 6; ++k) acc += Mb[i*6+k]*Mb[k*6+j]; Tb[tid]=acc; }
      __syncthreads();
      if (tid < 36) Mb[tid] = Tb[tid];
      __syncthreads();
    }
  }
  if (tid < 36) { Hs[tid] = (float)Rb[tid]; Mb[tid] = Rb[tid]; }
  __syncthreads();
  if (tid < 36) Rb[tid] = ((tid % 7) == 0) ? 1.0 : 0.0;
  __syncthreads();
  e = SEG;                                    // Rb = Hc^25 = A
  while (e) {
    if (e & 1) {
      double acc = 0.0;
      if (tid < 36) { for (int k = 0; k < 6; ++k) acc += Rb[i*6+k]*Mb[k*6+j]; Tb[tid]=acc; }
      __syncthreads();
      if (tid < 36) Rb[tid] = Tb[tid];
      __syncthreads();
    }
    e >>= 1;
    if (e) {
      double acc = 0.0;
      if (tid < 36) { for (int k = 0; k < 6; ++k) acc += Mb[i*6+k]*Mb[k*6+j]; Tb[tid]=acc; }
      __syncthreads();
      if (tid < 36) Mb[tid] = Tb[tid];
      __syncthreads();
    }
  }
  if (tid < 36) Gs[tid] = (float)Rb[tid];     // Gs[0] = A
  __syncthreads();
  for (int k = 1; k <= 6; ++k) {              // square: Gs[1..5], W64 = A^64
    double acc = 0.0;
    if (tid < 36) { for (int m = 0; m < 6; ++m) acc += Rb[i*6+m]*Rb[m*6+j]; Tb[tid]=acc; }
    __syncthreads();
    if (tid < 36) Rb[tid] = Tb[tid];
    __syncthreads();
    if (tid < 36) {
      if (k <= 5) Gs[k*36 + tid] = (float)Rb[tid];
      else        W64[tid]       = (float)Rb[tid];
    }
    __syncthreads();
  }

  float H[36];
  #pragma unroll
  for (int q = 0; q < 36; ++q) H[q] = Hs[q];
  const float* rbase = eoT + (size_t)row * RECROW;
  // local zero-entry scan over this thread's 25 chunks (coalesced reads)
  float u[6] = {0,0,0,0,0,0};
  for (int jj = 0; jj < SEG; ++jj) {
    const float* ep = rbase + ((size_t)(jj*TPB + tid))*8;
    float4 r0 = *(const float4*)ep, r1 = *(const float4*)(ep+4);
    float ev[6] = {r0.x,r0.y,r0.z,r0.w,r1.x,r1.y};
    float nu[6];
    #pragma unroll
    for (int q = 0; q < 6; ++q) {
      float a = ev[q];
      #pragma unroll
      for (int m = 0; m < 6; ++m) a += H[q*6+m]*u[m];
      nu[q] = a;
    }
    #pragma unroll
    for (int q = 0; q < 6; ++q) u[q] = nu[q];
  }
  // wave KS #1 (multipliers A^(2^k)) -> wave totals
  float v6[6];
  #pragma unroll
  for (int q = 0; q < 6; ++q) v6[q] = u[q];
  #pragma unroll
  for (int k = 0; k < 6; ++k) {
    const float* G = Gs + k*36;
    float o[6];
    #pragma unroll
    for (int q = 0; q < 6; ++q) o[q] = __shfl_up(v6[q], 1u << k, 64);
    if (lane >= (1 << k)) {
      float nv[6];
      #pragma unroll
      for (int q = 0; q < 6; ++q) {
        float a = v6[q];
        #pragma unroll
        for (int m = 0; m < 6; ++m) a += G[q*6+m]*o[m];
        nv[q] = a;
      }
      #pragma unroll
      for (int q = 0; q < 6; ++q) v6[q] = nv[q];
    }
  }
  if (lane == 63) {
    #pragma unroll
    for (int q = 0; q < 6; ++q) wtot[w][q] = v6[q];
  }
  __syncthreads();
  // per-wave entry S_w (row entry = 0; fold previous waves through W64)
  float S[6] = {0,0,0,0,0,0};
  for (int ww = 0; ww < w; ++ww) {
    float nS[6];
    #pragma unroll
    for (int q = 0; q < 6; ++q) {
      float a = wtot[ww][q];
      #pragma unroll
      for (int m = 0; m < 6; ++m) a += W64[q*6+m]*S[m];
      nS[q] = a;
    }
    #pragma unroll
    for (int q = 0; q < 6; ++q) S[q] = nS[q];
  }
  // lane-0 injection (u0 += A*S_w), KS #2 -> per-thread true entries
  if (lane == 0) {
    const float* A = Gs;                 // Gs[0] = Hc^25
    float nu[6];
    #pragma unroll
    for (int q = 0; q < 6; ++q) {
      float a = u[q];
      #pragma unroll
      for (int m = 0; m < 6; ++m) a += A[q*6+m]*S[m];
      nu[q] = a;
    }
    #pragma unroll
    for (int q = 0; q < 6; ++q) u[q] = nu[q];
  }
  #pragma unroll
  for (int q = 0; q < 6; ++q) v6[q] = u[q];
  #pragma unroll
  for (int k = 0; k < 6; ++k) {
    const float* G = Gs + k*36;
    float o[6];
    #pragma unroll
    for (int q = 0; q < 6; ++q) o[q] = __shfl_up(v6[q], 1u << k, 64);
    if (lane >= (1 << k)) {
      float nv[6];
      #pragma unroll
      for (int q = 0; q < 6; ++q) {
        float a = v6[q];
        #pragma unroll
        for (int m = 0; m < 6; ++m) a += G[q*6+m]*o[m];
        nv[q] = a;
      }
      #pragma unroll
      for (int q = 0; q < 6; ++q) v6[q] = nv[q];
    }
  }
  float s[6];
  #pragma unroll
  for (int q = 0; q < 6; ++q) s[q] = __shfl_up(v6[q], 1, 64);
  if (lane == 0) {
    #pragma unroll
    for (int q = 0; q < 6; ++q) s[q] = S[q];
  }
  // replay: write true entry of chunk c = tid*25+jj (direct layout)
  float* wbase = sgD + (size_t)row * RECROW;
  for (int jj = 0; jj < SEG; ++jj) {
    const float* ep = rbase + ((size_t)(jj*TPB + tid))*8;
    float4 r0 = *(const float4*)ep, r1 = *(const float4*)(ep+4);
    float ev[6] = {r0.x,r0.y,r0.z,r0.w,r1.x,r1.y};
    float* wp = wbase + ((size_t)(tid*SEG + jj))*8;
    float4 w0; w0.x=s[0]; w0.y=s[1]; w0.z=s[2]; w0.w=s[3];
    float4 w1; w1.x=s[4]; w1.y=s[5]; w1.z=0.f; w1.w=0.f;
    *(float4*)wp = w0; *(float4*)(wp+4) = w1;
    float ns[6];
    #pragma unroll
    for (int q = 0; q < 6; ++q) {
      float a = ev[q];
      #pragma unroll
      for (int m = 0; m < 6; ++m) a += H[q*6+m]*s[m];
      ns[q] = a;
    }
    #pragma unroll
    for (int q = 0; q < 6; ++q) s[q] = ns[q];
  }
}

// ---------------------------------------------------------------------------
// C: 4-wave LDS-tile exact cascade with true entry (coalesced sgD read);
// in-place y in tile, coop-store. Barrier between cross-thread history reads
// and in-place IIR (readers/writers may be in different waves).
// ---------------------------------------------------------------------------
__global__ __launch_bounds__(TPB) void eq_c(
    const float* __restrict__ x, const float* __restrict__ fr,
    const float* __restrict__ gn, const float* __restrict__ qs,
    const float* __restrict__ sgD, float* __restrict__ y)
{
  __shared__ float lds[TILEF];
  const int tid = threadIdx.x;
  const int b = blockIdx.x;
  const int row = b / BPR;
  const int ci = (b % BPR) * TPB + tid;
  float c[15];
  coeffs_f32(fr, gn, qs, c);
  const float4* xg4 = (const float4*)(x + (size_t)b * TILEF);
  float4* l4 = (float4*)lds;
  #pragma unroll
  for (int it = 0; it < 6; ++it) l4[it*TPB + tid] = xg4[it*TPB + tid];
  if (tid < 64) l4[1536 + tid] = xg4[1536 + tid];
  const float* sp = sgD + (size_t)row * RECROW + (size_t)ci * 8;
  float4 s0 = *(const float4*)sp, s1 = *(const float4*)(sp+4);
  __syncthreads();
  float x1, x2;
  if (tid == 0) {
    if (ci == 0) { x1 = 0.f; x2 = 0.f; }
    else {
      float2 h = *(const float2*)(x + (size_t)b * TILEF - 2);
      x1 = h.y; x2 = h.x;
    }
  } else {
    x1 = lds[tid*CL - 1]; x2 = lds[tid*CL - 2];
  }
  __syncthreads();     // cross-wave history reads done before in-place writes
  float y1p=s0.x, y1pp=s0.y, y2p=s0.z, y2pp=s0.w, y3p=s1.x, y3pp=s1.y;
  float* myrow = &lds[tid * CL];
  #pragma unroll
  for (int k = 0; k < CL; ++k) {
    float o_;
    STEPR(myrow[k], o_);
    myrow[k] = o_;
  }
  __syncthreads();
  float4* yg4 = (float4*)(y + (size_t)b * TILEF);
  #pragma unroll
  for (int it = 0; it < 6; ++it) yg4[it*TPB + tid] = l4[it*TPB + tid];
  if (tid < 64) yg4[1536 + tid] = l4[1536 + tid];
}

// ws: eoT [0, 26.2MB) | sgD [26.2MB, 52.4MB)
extern "C" void kernel_launch(void* const* d_in, const int* in_sizes, int n_in,
                              void* d_out, int out_size, void* d_ws, size_t ws_size,
                              hipStream_t stream) {
  const float* clip = (const float*)d_in[0];
  const float* fr   = (const float*)d_in[1];
  const float* gn   = (const float*)d_in[2];
  const float* qs   = (const float*)d_in[3];
  float* out = (float*)d_out;
  float* eoT = (float*)d_ws;
  float* sgD = eoT + (size_t)NB * RECROW;

  eq_a<<<NBLK, TPB, 0, stream>>>(clip, fr, gn, qs, eoT);
  eq_b<<<NB, TPB, 0, stream>>>(fr, gn, qs, eoT, sgD);
  eq_c<<<NBLK, TPB, 0, stream>>>(clip, fr, gn, qs, sgD, out);
}